// Round 6
// baseline (396.175 us; speedup 1.0000x reference)
//
#include <hip/hip_runtime.h>
#include <math.h>

#define BB    4
#define TT    1024
#define EE    1024
#define HH    16
#define HDIM  64
#define SS    2048
#define MROWS 4096
#define SCALEQ 0.125f

typedef short  s8v  __attribute__((ext_vector_type(8)));
typedef float  f4v  __attribute__((ext_vector_type(4)));
typedef float  f16v __attribute__((ext_vector_type(16)));

__device__ __forceinline__ unsigned short f2bf(float f) {
    union { float f; unsigned u; } c; c.f = f;
    unsigned u = c.u + 0x7FFFu + ((c.u >> 16) & 1u);
    return (unsigned short)(u >> 16);
}
__device__ __forceinline__ float bf2f(unsigned short h) {
    union { unsigned u; float f; } c; c.u = ((unsigned)h) << 16;
    return c.f;
}

__device__ __forceinline__ void async16(const void* g, void* l) {
    __builtin_amdgcn_global_load_lds(
        (const __attribute__((address_space(1))) unsigned int*)g,
        (__attribute__((address_space(3))) unsigned int*)l,
        16, 0, 0);
}

// ---------------------------------------------------------------------------
__global__ __launch_bounds__(256) void cvt6_kernel(
    const float* __restrict__ x,  const float* __restrict__ wq,
    const float* __restrict__ wk, const float* __restrict__ wv,
    const float* __restrict__ wo, const float* __restrict__ mk,
    unsigned short* __restrict__ xb,  unsigned short* __restrict__ wqb,
    unsigned short* __restrict__ wkb, unsigned short* __restrict__ wvb,
    unsigned short* __restrict__ wob, unsigned short* __restrict__ mbb)
{
    const int total = 3670016;
    int i = blockIdx.x * 256 + threadIdx.x;
    const int stride = gridDim.x * 256;
    for (; i < total; i += stride) {
        const float* s; unsigned short* d; int off;
        if (i < 1048576)      { s = x;  d = xb;  off = i; }
        else if (i < 1310720) { s = wq; d = wqb; off = i - 1048576; }
        else if (i < 1835008) { s = wk; d = wkb; off = i - 1310720; }
        else if (i < 2359296) { s = wv; d = wvb; off = i - 1835008; }
        else if (i < 2621440) { s = wo; d = wob; off = i - 2359296; }
        else                  { s = mk; d = mbb; off = i - 2621440; }
        float4 v = ((const float4*)s)[off];
        ushort4 o;
        o.x = f2bf(v.x); o.y = f2bf(v.y); o.z = f2bf(v.z); o.w = f2bf(v.w);
        ((ushort4*)d)[off] = o;
    }
}

// ---------------------------------------------------------------------------
#define GEMM_KLOOP(Aptr, Wptr, Ksz)                                            \
    for (int k0 = 0; k0 < (Ksz); k0 += 32) {                                   \
        _Pragma("unroll")                                                      \
        for (int it = 0; it < 2; ++it) {                                       \
            int f = (it * 4 + w) * 64 + lane;                                  \
            int r = f >> 2, g = (f & 3) * 8;                                   \
            async16((Aptr) + (size_t)r * (Ksz) + k0 + g,                       \
                    As + (it * 4 + w) * 512);                                  \
            async16((Wptr) + (size_t)r * (Ksz) + k0 + g,                       \
                    Bs + (it * 4 + w) * 512);                                  \
        }                                                                      \
        __syncthreads();                                                       \
        s8v af[4], bf[4];                                                      \
        _Pragma("unroll")                                                      \
        for (int i = 0; i < 4; ++i)                                            \
            af[i] = *(const s8v*)(As + (wm + i * 16 + col16) * 32 + quad * 8); \
        _Pragma("unroll")                                                      \
        for (int j = 0; j < 4; ++j)                                            \
            bf[j] = *(const s8v*)(Bs + (wn + j * 16 + col16) * 32 + quad * 8); \
        _Pragma("unroll")                                                      \
        for (int i = 0; i < 4; ++i)                                            \
            _Pragma("unroll")                                                  \
            for (int j = 0; j < 4; ++j)                                        \
                acc[i][j] = __builtin_amdgcn_mfma_f32_16x16x32_bf16(           \
                    af[i], bf[j], acc[i][j], 0, 0, 0);                         \
        __syncthreads();                                                       \
    }

// ---------------------------------------------------------------------------
// Fused Q+K+V projection, 1280 blocks:
//   gid<256: Q -> qp plain; gid<768: K -> kp [B,H,S,HD]; else V^T -> vt [B,H,HD,S]
// ---------------------------------------------------------------------------
__global__ __launch_bounds__(256, 3) void gemm_qkv_kernel(
    const unsigned short* __restrict__ X,
    const unsigned short* __restrict__ Wq, const unsigned short* __restrict__ Wk,
    const unsigned short* __restrict__ Wv,
    const float* __restrict__ bq, const float* __restrict__ bk,
    const float* __restrict__ bv,
    unsigned short* __restrict__ qp, unsigned short* __restrict__ kp,
    unsigned short* __restrict__ vt)
{
    __shared__ __align__(16) unsigned short As[128 * 32];
    __shared__ __align__(16) unsigned short Bs[128 * 32];

    const int tid = threadIdx.x;
    const int lane = tid & 63, w = tid >> 6;
    const int wm = (w & 1) * 64, wn = (w >> 1) * 64;
    const int col16 = lane & 15, quad = lane >> 4;

    const int gid = blockIdx.x;
    int mode, mi, ni;
    const unsigned short *Ab, *Bb;
    if (gid < 256) {
        mode = 0; mi = gid >> 3; ni = gid & 7;
        Ab = X + (size_t)mi * 128 * EE;  Bb = Wq + (size_t)ni * 128 * EE;
    } else if (gid < 768) {
        int g = gid - 256; mode = 1; mi = g >> 4; ni = g & 15;
        Ab = X + (size_t)mi * 128 * EE;  Bb = Wk + (size_t)ni * 128 * EE;
    } else {
        int g = gid - 768; mode = 2; mi = g & 15; ni = g >> 4;
        Ab = Wv + (size_t)mi * 128 * EE; Bb = X + (size_t)ni * 128 * EE;
    }

    f4v acc[4][4];
#pragma unroll
    for (int i = 0; i < 4; ++i)
#pragma unroll
        for (int j = 0; j < 4; ++j) acc[i][j] = (f4v)0.0f;

    GEMM_KLOOP(Ab, Bb, EE)

#pragma unroll
    for (int j = 0; j < 4; ++j) {
        const int nl = wn + j * 16 + col16;
#pragma unroll
        for (int i = 0; i < 4; ++i) {
#pragma unroll
            for (int r = 0; r < 4; ++r) {
                const int ml = wm + i * 16 + quad * 4 + r;
                float c = acc[i][j][r];
                if (mode == 0) {
                    const int m = mi * 128 + ml, n = ni * 128 + nl;
                    qp[(size_t)m * EE + n] = f2bf((c + bq[n]) * SCALEQ);
                } else if (mode == 1) {
                    const int m = mi * 128 + ml, nk = ni * 128 + nl;
                    const int mm = nk >> 10, h = (nk >> 6) & 15, d = nk & 63;
                    const int b_ = m >> 10, t = m & 1023;
                    const int s = 2 * t + mm;
                    kp[((size_t)(b_ * HH + h) * SS + s) * HDIM + d] = f2bf(c + bk[nk]);
                } else {
                    const int f = mi * 128 + ml, tok = ni * 128 + nl;
                    const int mm = f >> 10, h = (f >> 6) & 15, d = f & 63;
                    const int b_ = tok >> 10, t = tok & 1023;
                    const int s = 2 * t + mm;
                    vt[((size_t)(b_ * HH + h) * HDIM + d) * SS + s] = f2bf(c + bv[f]);
                }
            }
        }
    }
}

// ---------------------------------------------------------------------------
template <int OUTF32, int Ksz, int Nsz>
__global__ __launch_bounds__(256, 3) void gemm_mfma_kernel(
    const unsigned short* __restrict__ A, const unsigned short* __restrict__ W,
    const float* __restrict__ bias, void* __restrict__ Cout, float alpha)
{
    __shared__ __align__(16) unsigned short As[128 * 32];
    __shared__ __align__(16) unsigned short Bs[128 * 32];

    const int tid = threadIdx.x;
    const int lane = tid & 63, w = tid >> 6;
    const int wm = (w & 1) * 64, wn = (w >> 1) * 64;
    const int col16 = lane & 15, quad = lane >> 4;
    const unsigned short* Ab = A + (size_t)blockIdx.x * 128 * Ksz;
    const unsigned short* Bb = W + (size_t)blockIdx.y * 128 * Ksz;

    f4v acc[4][4];
#pragma unroll
    for (int i = 0; i < 4; ++i)
#pragma unroll
        for (int j = 0; j < 4; ++j) acc[i][j] = (f4v)0.0f;

    GEMM_KLOOP(Ab, Bb, Ksz)

#pragma unroll
    for (int j = 0; j < 4; ++j) {
        const int n = blockIdx.y * 128 + wn + j * 16 + col16;
        const float bn = bias[n];
#pragma unroll
        for (int i = 0; i < 4; ++i) {
#pragma unroll
            for (int r = 0; r < 4; ++r) {
                const int m = blockIdx.x * 128 + wm + i * 16 + quad * 4 + r;
                float c = (acc[i][j][r] + bn) * alpha;
                if (OUTF32) ((float*)Cout)[(size_t)m * Nsz + n] = c;
                else ((unsigned short*)Cout)[(size_t)m * Nsz + n] = f2bf(c);
            }
        }
    }
}

// ---------------------------------------------------------------------------
// Flash attention v3: mfma_32x32x16, S^T / O^T formulation. See theory.
// Block = (bh, 128 t); wave w owns t-tile w*32..w*32+31. 2 blocks/CU.
// ---------------------------------------------------------------------------
__global__ __launch_bounds__(256, 2) void attn_mfma32_kernel(
    const unsigned short* __restrict__ Q, const unsigned short* __restrict__ Kh,
    const unsigned short* __restrict__ Vt, const unsigned short* __restrict__ Mb,
    unsigned short* __restrict__ O)
{
    constexpr int PT = 68;    // 136B pitch: 2-way banks (R5: conflicts 0)
    constexpr int PP = 132;   // P pitch: 264B, 2-way banks
    // KM arena: K0(64*PT) | K1(64*PT) | Ms(128*PT) = 17408 ushorts;
    // aliased by P (128*PP = 16896 ushorts <= 17408). Total LDS 71808 B.
    __shared__ __align__(16) unsigned short Qs[128 * PT];
    __shared__ __align__(16) unsigned short KM[256 * PT];
    __shared__ __align__(16) unsigned short V0s[64 * PT];
    __shared__ __align__(16) unsigned short V1s[64 * PT];

    const int tid = threadIdx.x;
    const int lane = tid & 63, w = tid >> 6;
    const int l31 = lane & 31;
    const int h8 = (lane >> 5) * 8;   // k-offset in A/B frags
    const int h4 = (lane >> 5) * 4;   // row-offset in C tiles

    const int gid = blockIdx.x;
    const int v = gid & 7, j = gid >> 3;
    const int bh = v * 8 + (j & 7);
    const int t0 = (j >> 3) * 128;
    const int b_ = bh >> 4, h = bh & 15;

    unsigned short* K0 = KM;
    unsigned short* K1 = KM + 64 * PT;
    unsigned short* Ms = KM + 128 * PT;
    unsigned short* P  = KM;          // aliased, pitch PP

    // stage Q [128 t][64 d] once
#pragma unroll
    for (int st = 0; st < 4; ++st) {
        int idx = tid + st * 256;
        int r = idx >> 3, c = (idx & 7) * 8;
        *(uint4*)(Qs + r * PT + c) =
            *(const uint4*)(Q + (size_t)(b_ * TT + t0 + r) * EE + h * HDIM + c);
    }

    f16v oacc[2];
    oacc[0] = (f16v)0.0f; oacc[1] = (f16v)0.0f;
    float mrun = -INFINITY, lrun = 0.0f;

    const unsigned short* Kb  = Kh + (size_t)bh * SS * HDIM;
    const unsigned short* Vb  = Vt + (size_t)bh * HDIM * SS;
    const unsigned short* Mbb = Mb + (size_t)b_ * TT * TT;

    const int trow = w * 32 + l31;
    const int qrow = trow * PT;
    const int prow = trow * PP;

    for (int it = 0; it < 16; ++it) {
        const int t2b = it * 64;
        __syncthreads();  // (A)
#pragma unroll
        for (int st = 0; st < 2; ++st) {
            int idx = tid + st * 256;
            int r = idx >> 3, c = (idx & 7) * 8;
            *(uint4*)(K0 + r * PT + c)  = *(const uint4*)(Kb + (size_t)(t2b + r) * HDIM + c);
            *(uint4*)(K1 + r * PT + c)  = *(const uint4*)(Kb + (size_t)(1024 + t2b + r) * HDIM + c);
            *(uint4*)(V0s + r * PT + c) = *(const uint4*)(Vb + (size_t)r * SS + t2b + c);
            *(uint4*)(V1s + r * PT + c) = *(const uint4*)(Vb + (size_t)r * SS + 1024 + t2b + c);
        }
#pragma unroll
        for (int st = 0; st < 4; ++st) {
            int idx = tid + st * 256;
            int r = idx >> 3, c = (idx & 7) * 8;
            *(uint4*)(Ms + r * PT + c) = *(const uint4*)(Mbb + (size_t)(t0 + r) * TT + t2b + c);
        }
        __syncthreads();  // (B)

        f16v sacc[4];
#pragma unroll
        for (int js = 0; js < 4; ++js) sacc[js] = (f16v)0.0f;
#pragma unroll
        for (int kk = 0; kk < 4; ++kk) {
            s8v qf = *(const s8v*)(Qs + qrow + kk * 16 + h8);
#pragma unroll
            for (int js = 0; js < 4; ++js) {
                const unsigned short* kt = (js < 2) ? K0 : K1;
                s8v kf = *(const s8v*)(kt + ((js & 1) * 32 + l31) * PT + kk * 16 + h8);
                sacc[js] = __builtin_amdgcn_mfma_f32_32x32x16_bf16(kf, qf, sacc[js], 0, 0, 0);
            }
        }

        uint2 mu[2][4];
#pragma unroll
        for (int jh = 0; jh < 2; ++jh)
#pragma unroll
            for (int q = 0; q < 4; ++q)
                mu[jh][q] = *(const uint2*)(Ms + qrow + jh * 32 + 8 * q + h4);
#pragma unroll
        for (int js = 0; js < 4; ++js)
#pragma unroll
            for (int q = 0; q < 4; ++q) {
                uint2 m2 = mu[js & 1][q];
                sacc[js][4 * q + 0] += bf2f((unsigned short)(m2.x & 0xffff));
                sacc[js][4 * q + 1] += bf2f((unsigned short)(m2.x >> 16));
                sacc[js][4 * q + 2] += bf2f((unsigned short)(m2.y & 0xffff));
                sacc[js][4 * q + 3] += bf2f((unsigned short)(m2.y >> 16));
            }

        float tmax = -INFINITY;
#pragma unroll
        for (int js = 0; js < 4; ++js)
#pragma unroll
            for (int e = 0; e < 16; ++e) tmax = fmaxf(tmax, sacc[js][e]);
        tmax = fmaxf(tmax, __shfl_xor(tmax, 32));
        const float mnew = fmaxf(mrun, tmax);
        const float scl = __expf(mrun - mnew);
        float rs = 0.0f;
#pragma unroll
        for (int js = 0; js < 4; ++js)
#pragma unroll
            for (int e = 0; e < 16; ++e) {
                float p = __expf(sacc[js][e] - mnew);
                sacc[js][e] = p;
                rs += p;
            }
        rs += __shfl_xor(rs, 32);
        lrun = lrun * scl + rs;
        mrun = mnew;
        oacc[0] *= scl;
        oacc[1] *= scl;

        __syncthreads();  // (C)

#pragma unroll
        for (int js = 0; js < 4; ++js)
#pragma unroll
            for (int q = 0; q < 4; ++q) {
                unsigned p01 = (unsigned)f2bf(sacc[js][4 * q + 0]) |
                               ((unsigned)f2bf(sacc[js][4 * q + 1]) << 16);
                unsigned p23 = (unsigned)f2bf(sacc[js][4 * q + 2]) |
                               ((unsigned)f2bf(sacc[js][4 * q + 3]) << 16);
                *(uint2*)(P + prow + js * 32 + 8 * q + h4) = make_uint2(p01, p23);
            }
        __syncthreads();  // (D)

#pragma unroll
        for (int ks = 0; ks < 8; ++ks) {
            const unsigned short* vtile = (ks < 4) ? V0s : V1s;
            const int ko = (ks & 3) * 16 + h8;
            s8v pf  = *(const s8v*)(P + prow + ks * 16 + h8);
            s8v vf0 = *(const s8v*)(vtile + l31 * PT + ko);
            s8v vf1 = *(const s8v*)(vtile + (32 + l31) * PT + ko);
            oacc[0] = __builtin_amdgcn_mfma_f32_32x32x16_bf16(vf0, pf, oacc[0], 0, 0, 0);
            oacc[1] = __builtin_amdgcn_mfma_f32_32x32x16_bf16(vf1, pf, oacc[1], 0, 0, 0);
        }
    }

    const float inv = 1.0f / lrun;
    const int tg = t0 + trow;
#pragma unroll
    for (int jd = 0; jd < 2; ++jd)
#pragma unroll
        for (int q = 0; q < 4; ++q) {
            unsigned p01 = (unsigned)f2bf(oacc[jd][4 * q + 0] * inv) |
                           ((unsigned)f2bf(oacc[jd][4 * q + 1] * inv) << 16);
            unsigned p23 = (unsigned)f2bf(oacc[jd][4 * q + 2] * inv) |
                           ((unsigned)f2bf(oacc[jd][4 * q + 3] * inv) << 16);
            *(uint2*)(O + (size_t)(b_ * TT + tg) * EE + h * HDIM + jd * 32 + 8 * q + h4) =
                make_uint2(p01, p23);
        }
}

// ---------------------------------------------------------------------------
extern "C" void kernel_launch(void* const* d_in, const int* in_sizes, int n_in,
                              void* d_out, int out_size, void* d_ws, size_t ws_size,
                              hipStream_t stream)
{
    (void)in_sizes; (void)n_in; (void)out_size; (void)ws_size;

    const float* x    = (const float*)d_in[0];
    const float* mask = (const float*)d_in[1];
    const float* Wq   = (const float*)d_in[2];
    const float* bq   = (const float*)d_in[3];
    const float* Wk   = (const float*)d_in[4];
    const float* bk   = (const float*)d_in[5];
    const float* Wv   = (const float*)d_in[6];
    const float* bv   = (const float*)d_in[7];
    const float* Wo   = (const float*)d_in[8];
    const float* bo   = (const float*)d_in[9];
    float* out = (float*)d_out;

    unsigned short* xb  = (unsigned short*)d_ws;
    unsigned short* wqb = xb  + (size_t)MROWS * EE;
    unsigned short* wkb = wqb + (size_t)EE * EE;
    unsigned short* wvb = wkb + (size_t)2 * EE * EE;
    unsigned short* wob = wvb + (size_t)2 * EE * EE;
    unsigned short* mb  = wob + (size_t)EE * EE;
    unsigned short* qp  = mb  + (size_t)BB * TT * TT;
    unsigned short* kp  = qp  + (size_t)MROWS * EE;
    unsigned short* vt  = kp  + (size_t)BB * HH * SS * HDIM;
    unsigned short* ao  = vt  + (size_t)BB * HH * SS * HDIM;

    dim3 blk(256);

    cvt6_kernel<<<4096, blk, 0, stream>>>(x, Wq, Wk, Wv, Wo, mask,
                                          xb, wqb, wkb, wvb, wob, mb);
    gemm_qkv_kernel<<<dim3(1280), blk, 0, stream>>>(
        xb, wqb, wkb, wvb, bq, bk, bv, qp, kp, vt);
    attn_mfma32_kernel<<<dim3(512), blk, 0, stream>>>(qp, kp, vt, mb, ao);
    gemm_mfma_kernel<1, EE, EE><<<dim3(32, 8), blk, 0, stream>>>(
        ao, wob, bo, out, 1.0f);
}

// Round 7
// 343.927 us; speedup vs baseline: 1.1519x; 1.1519x over previous
//
#include <hip/hip_runtime.h>
#include <math.h>

#define BB    4
#define TT    1024
#define EE    1024
#define HH    16
#define HDIM  64
#define SS    2048
#define MROWS 4096
#define SCALEQ 0.125f

typedef short  s8v  __attribute__((ext_vector_type(8)));
typedef float  f4v  __attribute__((ext_vector_type(4)));

__device__ __forceinline__ unsigned short f2bf(float f) {
    union { float f; unsigned u; } c; c.f = f;
    unsigned u = c.u + 0x7FFFu + ((c.u >> 16) & 1u);
    return (unsigned short)(u >> 16);
}
__device__ __forceinline__ float bf2f(unsigned short h) {
    union { unsigned u; float f; } c; c.u = ((unsigned)h) << 16;
    return c.f;
}

__device__ __forceinline__ void async16(const void* g, void* l) {
    __builtin_amdgcn_global_load_lds(
        (const __attribute__((address_space(1))) unsigned int*)g,
        (__attribute__((address_space(3))) unsigned int*)l,
        16, 0, 0);
}

// ---------------------------------------------------------------------------
// Fused fp32->bf16 convert: x, Wq, Wk, Wv, Wo, mask.
// ---------------------------------------------------------------------------
__global__ __launch_bounds__(256) void cvt6_kernel(
    const float* __restrict__ x,  const float* __restrict__ wq,
    const float* __restrict__ wk, const float* __restrict__ wv,
    const float* __restrict__ wo, const float* __restrict__ mk,
    unsigned short* __restrict__ xb,  unsigned short* __restrict__ wqb,
    unsigned short* __restrict__ wkb, unsigned short* __restrict__ wvb,
    unsigned short* __restrict__ wob, unsigned short* __restrict__ mbb)
{
    const int total = 3670016;
    int i = blockIdx.x * 256 + threadIdx.x;
    const int stride = gridDim.x * 256;
    for (; i < total; i += stride) {
        const float* s; unsigned short* d; int off;
        if (i < 1048576)      { s = x;  d = xb;  off = i; }
        else if (i < 1310720) { s = wq; d = wqb; off = i - 1048576; }
        else if (i < 1835008) { s = wk; d = wkb; off = i - 1310720; }
        else if (i < 2359296) { s = wv; d = wvb; off = i - 1835008; }
        else if (i < 2621440) { s = wo; d = wob; off = i - 2359296; }
        else                  { s = mk; d = mbb; off = i - 2621440; }
        float4 v = ((const float4*)s)[off];
        ushort4 o;
        o.x = f2bf(v.x); o.y = f2bf(v.y); o.z = f2bf(v.z); o.w = f2bf(v.w);
        ((ushort4*)d)[off] = o;
    }
}

// ---------------------------------------------------------------------------
#define GEMM_KLOOP(Aptr, Wptr, Ksz)                                            \
    for (int k0 = 0; k0 < (Ksz); k0 += 32) {                                   \
        _Pragma("unroll")                                                      \
        for (int it = 0; it < 2; ++it) {                                       \
            int f = (it * 4 + w) * 64 + lane;                                  \
            int r = f >> 2, g = (f & 3) * 8;                                   \
            async16((Aptr) + (size_t)r * (Ksz) + k0 + g,                       \
                    As + (it * 4 + w) * 512);                                  \
            async16((Wptr) + (size_t)r * (Ksz) + k0 + g,                       \
                    Bs + (it * 4 + w) * 512);                                  \
        }                                                                      \
        __syncthreads();                                                       \
        s8v af[4], bf[4];                                                      \
        _Pragma("unroll")                                                      \
        for (int i = 0; i < 4; ++i)                                            \
            af[i] = *(const s8v*)(As + (wm + i * 16 + col16) * 32 + quad * 8); \
        _Pragma("unroll")                                                      \
        for (int j = 0; j < 4; ++j)                                            \
            bf[j] = *(const s8v*)(Bs + (wn + j * 16 + col16) * 32 + quad * 8); \
        _Pragma("unroll")                                                      \
        for (int i = 0; i < 4; ++i)                                            \
            _Pragma("unroll")                                                  \
            for (int j = 0; j < 4; ++j)                                        \
                acc[i][j] = __builtin_amdgcn_mfma_f32_16x16x32_bf16(           \
                    af[i], bf[j], acc[i][j], 0, 0, 0);                         \
        __syncthreads();                                                       \
    }

// ---------------------------------------------------------------------------
// Fused Q+K+V projection, 1280 blocks:
//   gid<256: Q -> qp plain; gid<768: K -> kp [B,H,S,HD]; else V^T -> vt [B,H,HD,S]
// ---------------------------------------------------------------------------
__global__ __launch_bounds__(256, 4) void gemm_qkv_kernel(
    const unsigned short* __restrict__ X,
    const unsigned short* __restrict__ Wq, const unsigned short* __restrict__ Wk,
    const unsigned short* __restrict__ Wv,
    const float* __restrict__ bq, const float* __restrict__ bk,
    const float* __restrict__ bv,
    unsigned short* __restrict__ qp, unsigned short* __restrict__ kp,
    unsigned short* __restrict__ vt)
{
    __shared__ __align__(16) unsigned short As[128 * 32];
    __shared__ __align__(16) unsigned short Bs[128 * 32];

    const int tid = threadIdx.x;
    const int lane = tid & 63, w = tid >> 6;
    const int wm = (w & 1) * 64, wn = (w >> 1) * 64;
    const int col16 = lane & 15, quad = lane >> 4;

    const int gid = blockIdx.x;
    int mode, mi, ni;
    const unsigned short *Ab, *Bb;
    if (gid < 256) {
        mode = 0; mi = gid >> 3; ni = gid & 7;
        Ab = X + (size_t)mi * 128 * EE;  Bb = Wq + (size_t)ni * 128 * EE;
    } else if (gid < 768) {
        int g = gid - 256; mode = 1; mi = g >> 4; ni = g & 15;
        Ab = X + (size_t)mi * 128 * EE;  Bb = Wk + (size_t)ni * 128 * EE;
    } else {
        int g = gid - 768; mode = 2; mi = g & 15; ni = g >> 4;
        Ab = Wv + (size_t)mi * 128 * EE; Bb = X + (size_t)ni * 128 * EE;
    }

    f4v acc[4][4];
#pragma unroll
    for (int i = 0; i < 4; ++i)
#pragma unroll
        for (int j = 0; j < 4; ++j) acc[i][j] = (f4v)0.0f;

    GEMM_KLOOP(Ab, Bb, EE)

#pragma unroll
    for (int j = 0; j < 4; ++j) {
        const int nl = wn + j * 16 + col16;
#pragma unroll
        for (int i = 0; i < 4; ++i) {
#pragma unroll
            for (int r = 0; r < 4; ++r) {
                const int ml = wm + i * 16 + quad * 4 + r;
                float c = acc[i][j][r];
                if (mode == 0) {
                    const int m = mi * 128 + ml, n = ni * 128 + nl;
                    qp[(size_t)m * EE + n] = f2bf((c + bq[n]) * SCALEQ);
                } else if (mode == 1) {
                    const int m = mi * 128 + ml, nk = ni * 128 + nl;
                    const int mm = nk >> 10, h = (nk >> 6) & 15, d = nk & 63;
                    const int b_ = m >> 10, t = m & 1023;
                    const int s = 2 * t + mm;
                    kp[((size_t)(b_ * HH + h) * SS + s) * HDIM + d] = f2bf(c + bk[nk]);
                } else {
                    const int f = mi * 128 + ml, tok = ni * 128 + nl;
                    const int mm = f >> 10, h = (f >> 6) & 15, d = f & 63;
                    const int b_ = tok >> 10, t = tok & 1023;
                    const int s = 2 * t + mm;
                    vt[((size_t)(b_ * HH + h) * HDIM + d) * SS + s] = f2bf(c + bv[f]);
                }
            }
        }
    }
}

// ---------------------------------------------------------------------------
template <int OUTF32, int Ksz, int Nsz>
__global__ __launch_bounds__(256, 3) void gemm_mfma_kernel(
    const unsigned short* __restrict__ A, const unsigned short* __restrict__ W,
    const float* __restrict__ bias, void* __restrict__ Cout, float alpha)
{
    __shared__ __align__(16) unsigned short As[128 * 32];
    __shared__ __align__(16) unsigned short Bs[128 * 32];

    const int tid = threadIdx.x;
    const int lane = tid & 63, w = tid >> 6;
    const int wm = (w & 1) * 64, wn = (w >> 1) * 64;
    const int col16 = lane & 15, quad = lane >> 4;
    const unsigned short* Ab = A + (size_t)blockIdx.x * 128 * Ksz;
    const unsigned short* Bb = W + (size_t)blockIdx.y * 128 * Ksz;

    f4v acc[4][4];
#pragma unroll
    for (int i = 0; i < 4; ++i)
#pragma unroll
        for (int j = 0; j < 4; ++j) acc[i][j] = (f4v)0.0f;

    GEMM_KLOOP(Ab, Bb, Ksz)

#pragma unroll
    for (int j = 0; j < 4; ++j) {
        const int n = blockIdx.y * 128 + wn + j * 16 + col16;
        const float bn = bias[n];
#pragma unroll
        for (int i = 0; i < 4; ++i) {
#pragma unroll
            for (int r = 0; r < 4; ++r) {
                const int m = blockIdx.x * 128 + wm + i * 16 + quad * 4 + r;
                float c = (acc[i][j][r] + bn) * alpha;
                if (OUTF32) ((float*)Cout)[(size_t)m * Nsz + n] = c;
                else ((unsigned short*)Cout)[(size_t)m * Nsz + n] = f2bf(c);
            }
        }
    }
}

// ---------------------------------------------------------------------------
// Flash attention v4 = R5's verified 16x16 structure with:
//   - Q fragments in registers (loaded once; no Qs tile)
//   - V fragments direct from global (L2-resident via XCD swizzle; no V tiles)
// LDS = K0|K1|Ms (P aliases K0/K1) = 26.1 KB -> 4 blocks/CU, grid 1024 = 4x256
// exactly (no tail). All softmax/mask/P math identical to R5 (verified).
// ---------------------------------------------------------------------------
__global__ __launch_bounds__(256, 4) void attn_mfma4_kernel(
    const unsigned short* __restrict__ Q, const unsigned short* __restrict__ Kh,
    const unsigned short* __restrict__ Vt, const unsigned short* __restrict__ Mb,
    unsigned short* __restrict__ O)
{
    constexpr int PT = 68;   // 136B pitch (R5: 0 bank conflicts)
    __shared__ __align__(16) unsigned short K0[64 * PT];  // K half0, then P0
    __shared__ __align__(16) unsigned short K1[64 * PT];  // K half1, then P1
    __shared__ __align__(16) unsigned short Ms[64 * PT];  // mask [t][t2] bf16

    const int tid = threadIdx.x;
    const int lane = tid & 63, w = tid >> 6;
    const int col16 = lane & 15, quad = lane >> 4;

    // XCD swizzle (as R5): 8 consecutive bh per virtual XCD
    const int gid = blockIdx.x;
    const int v = gid & 7, j = gid >> 3;
    const int bh = v * 8 + (j >> 4);
    const int t0 = (j & 15) * 64;
    const int b_ = bh >> 4, h = bh & 15;

    const unsigned short* Kb  = Kh + (size_t)bh * SS * HDIM;
    const unsigned short* Vb  = Vt + (size_t)bh * HDIM * SS;
    const unsigned short* Mbb = Mb + (size_t)b_ * TT * TT;
    const int myrow = (w * 16 + col16) * PT;

    // Q fragments in registers: lane's A-frag row t = w*16+col16, k = ks*32+quad*8
    const unsigned short* Qrow = Q + (size_t)(b_ * TT + t0 + w * 16 + col16) * EE + h * HDIM;
    s8v qf[2];
    qf[0] = *(const s8v*)(Qrow + quad * 8);
    qf[1] = *(const s8v*)(Qrow + 32 + quad * 8);

    f4v oacc[4];
#pragma unroll
    for (int jd = 0; jd < 4; ++jd) oacc[jd] = (f4v)0.0f;
    float mrun = -INFINITY, lrun = 0.0f;

    for (int it16 = 0; it16 < 16; ++it16) {
        const int t2b = it16 * 64;
        __syncthreads();  // (A) prev iteration's P reads done
#pragma unroll
        for (int st = 0; st < 2; ++st) {
            int idx = tid + st * 256;
            int r = idx >> 3, c = (idx & 7) * 8;
            *(uint4*)(K0 + r * PT + c) = *(const uint4*)(Kb + (size_t)(t2b + r) * HDIM + c);
            *(uint4*)(K1 + r * PT + c) = *(const uint4*)(Kb + (size_t)(1024 + t2b + r) * HDIM + c);
            *(uint4*)(Ms + r * PT + c) = *(const uint4*)(Mbb + (size_t)(t0 + r) * TT + t2b + c);
        }
        __syncthreads();  // (B)

        // S^T halves: A=K (m=s), B=Q (n=t)
        f4v s0acc[4], s1acc[4];
#pragma unroll
        for (int js = 0; js < 4; ++js) { s0acc[js] = (f4v)0.0f; s1acc[js] = (f4v)0.0f; }
#pragma unroll
        for (int ks = 0; ks < 2; ++ks) {
            s8v bq_ = qf[ks];
#pragma unroll
            for (int js = 0; js < 4; ++js) {
                s8v ak0 = *(const s8v*)(K0 + (js * 16 + col16) * PT + ks * 32 + quad * 8);
                s8v ak1 = *(const s8v*)(K1 + (js * 16 + col16) * PT + ks * 32 + quad * 8);
                s0acc[js] = __builtin_amdgcn_mfma_f32_16x16x32_bf16(ak0, bq_, s0acc[js], 0, 0, 0);
                s1acc[js] = __builtin_amdgcn_mfma_f32_16x16x32_bf16(ak1, bq_, s1acc[js], 0, 0, 0);
            }
        }

        // mask add from LDS (bf16): lane's t-row, t2 = js*16+quad*4+r
#pragma unroll
        for (int js = 0; js < 4; ++js) {
            uint2 mm = *(const uint2*)(Ms + myrow + js * 16 + quad * 4);
            float m0f = bf2f((unsigned short)(mm.x & 0xffff));
            float m1f = bf2f((unsigned short)(mm.x >> 16));
            float m2f = bf2f((unsigned short)(mm.y & 0xffff));
            float m3f = bf2f((unsigned short)(mm.y >> 16));
            s0acc[js][0] += m0f; s1acc[js][0] += m0f;
            s0acc[js][1] += m1f; s1acc[js][1] += m1f;
            s0acc[js][2] += m2f; s1acc[js][2] += m2f;
            s0acc[js][3] += m3f; s1acc[js][3] += m3f;
        }

        // online softmax over 32 values (both halves) for this lane's t
        float tmax = -INFINITY;
#pragma unroll
        for (int js = 0; js < 4; ++js)
#pragma unroll
            for (int r = 0; r < 4; ++r)
                tmax = fmaxf(tmax, fmaxf(s0acc[js][r], s1acc[js][r]));
        tmax = fmaxf(tmax, __shfl_xor(tmax, 16));
        tmax = fmaxf(tmax, __shfl_xor(tmax, 32));
        const float mnew = fmaxf(mrun, tmax);
        const float scl = __expf(mrun - mnew);   // 0 on first tile
        float rs = 0.0f;
#pragma unroll
        for (int js = 0; js < 4; ++js)
#pragma unroll
            for (int r = 0; r < 4; ++r) {
                float p0 = __expf(s0acc[js][r] - mnew);
                float p1 = __expf(s1acc[js][r] - mnew);
                s0acc[js][r] = p0; s1acc[js][r] = p1;
                rs += p0 + p1;
            }
        rs += __shfl_xor(rs, 16);
        rs += __shfl_xor(rs, 32);
        lrun = lrun * scl + rs;
        mrun = mnew;

        // rescale O: oacc row t_local = quad*4+r; scl lives at lane col16=t_local
        float sclr[4];
#pragma unroll
        for (int r = 0; r < 4; ++r) sclr[r] = __shfl(scl, quad * 4 + r);
#pragma unroll
        for (int jd = 0; jd < 4; ++jd)
#pragma unroll
            for (int r = 0; r < 4; ++r) oacc[jd][r] *= sclr[r];

        __syncthreads();  // (C) all waves done reading K0/K1/Ms

        // store P halves [t][s_local] bf16 into K0/K1
#pragma unroll
        for (int js = 0; js < 4; ++js) {
            unsigned p01 = (unsigned)f2bf(s0acc[js][0]) | ((unsigned)f2bf(s0acc[js][1]) << 16);
            unsigned p23 = (unsigned)f2bf(s0acc[js][2]) | ((unsigned)f2bf(s0acc[js][3]) << 16);
            *(uint2*)(K0 + myrow + js * 16 + quad * 4) = make_uint2(p01, p23);
            p01 = (unsigned)f2bf(s1acc[js][0]) | ((unsigned)f2bf(s1acc[js][1]) << 16);
            p23 = (unsigned)f2bf(s1acc[js][2]) | ((unsigned)f2bf(s1acc[js][3]) << 16);
            *(uint2*)(K1 + myrow + js * 16 + quad * 4) = make_uint2(p01, p23);
        }
        __syncthreads();  // (D)

        // O += P0.V0 + P1.V1 : A=P from LDS, B=V direct from global (L2-hot)
#pragma unroll
        for (int ks = 0; ks < 2; ++ks) {
            s8v p0 = *(const s8v*)(K0 + myrow + ks * 32 + quad * 8);
            s8v p1 = *(const s8v*)(K1 + myrow + ks * 32 + quad * 8);
#pragma unroll
            for (int jd = 0; jd < 4; ++jd) {
                const unsigned short* vrow = Vb + (size_t)(jd * 16 + col16) * SS;
                s8v v0_ = *(const s8v*)(vrow + t2b + ks * 32 + quad * 8);
                s8v v1_ = *(const s8v*)(vrow + 1024 + t2b + ks * 32 + quad * 8);
                oacc[jd] = __builtin_amdgcn_mfma_f32_16x16x32_bf16(p0, v0_, oacc[jd], 0, 0, 0);
                oacc[jd] = __builtin_amdgcn_mfma_f32_16x16x32_bf16(p1, v1_, oacc[jd], 0, 0, 0);
            }
        }
    }

    // epilogue: normalize (gather 1/l for row t_local=quad*4+r) and write bf16
    const float inv = 1.0f / lrun;
    float invr[4];
#pragma unroll
    for (int r = 0; r < 4; ++r) invr[r] = __shfl(inv, quad * 4 + r);
#pragma unroll
    for (int r = 0; r < 4; ++r) {
        const int t = t0 + w * 16 + quad * 4 + r;
#pragma unroll
        for (int jd = 0; jd < 4; ++jd)
            O[(size_t)(b_ * TT + t) * EE + h * HDIM + jd * 16 + col16] =
                f2bf(oacc[jd][r] * invr[r]);
    }
}

// ---------------------------------------------------------------------------
extern "C" void kernel_launch(void* const* d_in, const int* in_sizes, int n_in,
                              void* d_out, int out_size, void* d_ws, size_t ws_size,
                              hipStream_t stream)
{
    (void)in_sizes; (void)n_in; (void)out_size; (void)ws_size;

    const float* x    = (const float*)d_in[0];
    const float* mask = (const float*)d_in[1];
    const float* Wq   = (const float*)d_in[2];
    const float* bq   = (const float*)d_in[3];
    const float* Wk   = (const float*)d_in[4];
    const float* bk   = (const float*)d_in[5];
    const float* Wv   = (const float*)d_in[6];
    const float* bv   = (const float*)d_in[7];
    const float* Wo   = (const float*)d_in[8];
    const float* bo   = (const float*)d_in[9];
    float* out = (float*)d_out;

    unsigned short* xb  = (unsigned short*)d_ws;
    unsigned short* wqb = xb  + (size_t)MROWS * EE;
    unsigned short* wkb = wqb + (size_t)EE * EE;
    unsigned short* wvb = wkb + (size_t)2 * EE * EE;
    unsigned short* wob = wvb + (size_t)2 * EE * EE;
    unsigned short* mb  = wob + (size_t)EE * EE;
    unsigned short* qp  = mb  + (size_t)BB * TT * TT;
    unsigned short* kp  = qp  + (size_t)MROWS * EE;
    unsigned short* vt  = kp  + (size_t)BB * HH * SS * HDIM;
    unsigned short* ao  = vt  + (size_t)BB * HH * SS * HDIM;

    dim3 blk(256);

    cvt6_kernel<<<4096, blk, 0, stream>>>(x, Wq, Wk, Wv, Wo, mask,
                                          xb, wqb, wkb, wvb, wob, mb);
    gemm_qkv_kernel<<<dim3(1280), blk, 0, stream>>>(
        xb, wqb, wkb, wvb, bq, bk, bv, qp, kp, vt);
    attn_mfma4_kernel<<<dim3(1024), blk, 0, stream>>>(qp, kp, vt, mb, ao);
    gemm_mfma_kernel<1, EE, EE><<<dim3(32, 8), blk, 0, stream>>>(
        ao, wob, bo, out, 1.0f);
}